// Round 2
// baseline (104.101 us; speedup 1.0000x reference)
//
#include <hip/hip_runtime.h>
#include <math.h>

#define EPS_F 1e-6f
#define S_DIM 768
#define W_DIM 32
#define H_DIM 12
#define NK 33   // intervals = W_DIM + 1

// ws float layout:
//   [0 .. 32)                      sorted hinge values (ascending)
//   [32 + h*2*NK + 2k]  = A_k(h)   (slope)
//   [32 + h*2*NK + 2k+1]= B_k(h)   (intercept, includes b_out[h])

// ---------------- setup: build sorted hinges + per-(h,k) PWL tables ----------
__global__ __launch_bounds__(512) void cope_setup_kernel(
    const float* __restrict__ W_in, const float* __restrict__ b_in,
    const float* __restrict__ W_out, const float* __restrict__ b_out,
    float* __restrict__ ws)
{
    __shared__ float th[W_DIM];
    __shared__ int   rk[W_DIM];
    const int t = threadIdx.x;

    if (t < W_DIM) {
        float w1 = W_in[t], b = b_in[t];
        th[t] = (w1 != 0.0f) ? (-b / w1) : __builtin_inff();
    }
    __syncthreads();

    if (t < W_DIM) {
        float mine = th[t];
        int r = 0;
        for (int v = 0; v < W_DIM; v++) {
            float o = th[v];
            if (o < mine || (o == mine && v < t)) r++;
        }
        rk[t] = r;          // sorted rank of hinge t (ties broken by index)
        ws[r] = mine;       // sorted hinge array
    }
    __syncthreads();

    if (t < H_DIM * NK) {
        int h = t / NK, k = t % NK;   // interval k: dist in (s[k-1], s[k])
        float A = 0.0f, B = b_out[h];
        for (int w = 0; w < W_DIM; w++) {
            float w1 = W_in[w], bv = b_in[w], ov = W_out[h * W_DIM + w];
            // relu(w1*d+bv) active on interval k?
            bool active = (w1 > 0.0f) ? (k > rk[w])
                        : (w1 < 0.0f) ? (k <= rk[w])
                        : (bv > 0.0f);
            if (active) { A += w1 * ov; B += bv * ov; }
        }
        ws[W_DIM + h * 2 * NK + 2 * k]     = A;
        ws[W_DIM + h * 2 * NK + 2 * k + 1] = B;
    }
}

// ---------------- main: wave-per-row, PWL evaluation ------------------------
__global__ __launch_bounds__(256) void cope_fire_kernel(
    const float* __restrict__ attn,   // (H*S, S)
    const float* __restrict__ c_p,
    const float* __restrict__ Lm_p,
    const float* __restrict__ iL_p,
    const float* __restrict__ ws,
    float* __restrict__ out)
{
    const int t    = threadIdx.x;
    const int lane = t & 63;
    const int wave = t >> 6;
    const int row  = blockIdx.x * 4 + wave;       // one wave per row
    const int h    = blockIdx.x / (S_DIM / 4);    // 192 blocks per h (uniform)

    __shared__ __align__(16) float sh[W_DIM];     // sorted hinges (16B-aligned for b128)
    __shared__ __align__(8)  float sAB[2 * NK];   // A,B pairs for this h

    if (t < W_DIM)  sh[t]  = ws[t];
    if (t < 2 * NK) sAB[t] = ws[W_DIM + h * 2 * NK + t];

    // uniform scalars (constant-index -> scalar loads)
    const float s3 = ws[3],  s7 = ws[7],  s11 = ws[11], s15 = ws[15];
    const float s19 = ws[19], s23 = ws[23], s27 = ws[27];
    const float c   = c_p[0];
    const float thr = fabsf(Lm_p[0] * iL_p[0]);

    // load 12 contiguous elements per lane (3x float4, 48B stride, all lines used)
    const float* rowp = attn + (size_t)row * S_DIM + lane * 12;
    float4 v0 = *(const float4*)(rowp);
    float4 v1 = *(const float4*)(rowp + 4);
    float4 v2 = *(const float4*)(rowp + 8);
    float g[12] = { v0.x, v0.y, v0.z, v0.w, v1.x, v1.y, v1.z, v1.w,
                    v2.x, v2.y, v2.z, v2.w };
#pragma unroll
    for (int i = 0; i < 12; i++)
        g[i] = __builtin_amdgcn_rcpf(1.0f + __expf(-g[i]));

    // lane total, inclusive wave scan over lane totals
    float T0 = 0.0f;
#pragma unroll
    for (int i = 0; i < 12; i++) T0 += g[i];
    float P = T0;
#pragma unroll
    for (int d = 1; d < 64; d <<= 1) {
        float y = __shfl_up(P, d, 64);
        if (lane >= d) P += y;
    }
    const float total = __shfl(P, 63, 64);
    const float base  = total - P + T0;   // suffix sum starting at lane's first elem

    const float den      = __logf(fabsf(c * fminf(total, thr)) + 1.0f) + EPS_F;
    // fold ln2 into inv_den so per-element log can be raw v_log_f32 (log2)
    const float inv_den2 = 0.69314718056f * __builtin_amdgcn_rcpf(den);

    __syncthreads();   // tables staged

    // ---- phase 1: all 12 dist values (independent log chains) ----
    float dv[12];
    {
        float e = 0.0f;
#pragma unroll
        for (int i = 0; i < 12; i++) {
            float pos = base - e;            // suffix sum at element i
            e += g[i];
            dv[i] = __log2f(fabsf(c * pos) + 1.0f) * inv_den2;
        }
    }

    // ---- phase 2: PWL search, two half-batches of 6 for explicit MLP ------
    // Per half-batch:
    //   (a) coarse k4 via register selects on uniform scalars (levels 16/8/4)
    //   (b) 6 independent ds_read_b128 of sh[k4..k4+3] issued back-to-back
    //   (c) resolve final k via selects, 6 independent ds_read_b64 of (A,B)
    //   (d) fma
    float o[12];
#pragma unroll
    for (int half = 0; half < 2; half++) {
        const int i0 = half * 6;

        int    k4[6];
        float4 r[6];
#pragma unroll
        for (int j = 0; j < 6; j++) {
            const float d = dv[i0 + j];
            int k = 0;
            bool b1 = (s15 < d);             if (b1) k += 16;
            float l2 = b1 ? s23 : s7;
            bool b2 = (l2 < d);              if (b2) k += 8;
            float l3a = b2 ? s11 : s3;
            float l3b = b2 ? s27 : s19;
            float l3  = b1 ? l3b : l3a;
            if (l3 < d) k += 4;
            k4[j] = k;                       // k in {0,4,...,28}
        }
        // (b) issue all 6 b128 reads (aligned; 8 distinct 16B slots tile banks)
#pragma unroll
        for (int j = 0; j < 6; j++)
            r[j] = *(const float4*)(&sh[k4[j]]);

        // (c) resolve and issue the 6 A/B reads
        float2 ab[6];
        float  dd[6];
#pragma unroll
        for (int j = 0; j < 6; j++) {
            const float d = dv[i0 + j];
            int k = k4[j];
            bool c2 = (r[j].y < d);          if (c2) k += 2;   // test s[k+1]
            float f1 = c2 ? r[j].z : r[j].x;                    // s[k] after +2 step
            bool c1 = (f1 < d);              if (c1) k += 1;
            float f0 = c1 ? (c2 ? r[j].w : r[j].y) : f1;        // s[k] after +1 step
            if (f0 < d) k += 1;              // final fixup -> k in [0,32]
            ab[j] = *(const float2*)(&sAB[2 * k]);
            dd[j] = d;
        }
        // (d) fma
#pragma unroll
        for (int j = 0; j < 6; j++)
            o[i0 + j] = fmaf(dd[j], ab[j].x, ab[j].y);
    }

    float* op = out + (size_t)row * S_DIM + lane * 12;
    *(float4*)(op)     = make_float4(o[0], o[1], o[2],  o[3]);
    *(float4*)(op + 4) = make_float4(o[4], o[5], o[6],  o[7]);
    *(float4*)(op + 8) = make_float4(o[8], o[9], o[10], o[11]);
}

extern "C" void kernel_launch(void* const* d_in, const int* in_sizes, int n_in,
                              void* d_out, int out_size, void* d_ws, size_t ws_size,
                              hipStream_t stream) {
    const float* attn  = (const float*)d_in[0];
    const float* W_in  = (const float*)d_in[1];
    const float* b_in  = (const float*)d_in[2];
    const float* W_out = (const float*)d_in[3];
    const float* b_out = (const float*)d_in[4];
    const float* c_p   = (const float*)d_in[5];
    const float* Lm_p  = (const float*)d_in[6];
    const float* iL_p  = (const float*)d_in[7];
    float* out = (float*)d_out;
    float* ws  = (float*)d_ws;

    cope_setup_kernel<<<1, 512, 0, stream>>>(W_in, b_in, W_out, b_out, ws);

    const int rows = H_DIM * S_DIM;            // 9216 rows, one wave each
    cope_fire_kernel<<<rows / 4, 256, 0, stream>>>(
        attn, c_p, Lm_p, iL_p, ws, out);
}

// Round 3
// 103.655 us; speedup vs baseline: 1.0043x; 1.0043x over previous
//
#include <hip/hip_runtime.h>
#include <math.h>

#define EPS_F 1e-6f
#define S_DIM 768
#define W_DIM 32
#define H_DIM 12
#define NK 33   // intervals = W_DIM + 1

// Fully fused: every block builds the (tiny) PWL tables for its own head h in
// LDS, then evaluates 4 rows (one wave per row). No setup kernel, no ws use.
//
// Table semantics (identical to the verified 2-kernel version):
//   sh[0..32)  sorted hinge values (ascending, ties by original index)
//   sAB[2k],sAB[2k+1] = A_k,B_k for interval k (dist in (s[k-1],s[k]]),
//   B_k includes b_out[h].

__global__ __launch_bounds__(256) void cope_fused_kernel(
    const float* __restrict__ attn,   // (H*S, S)
    const float* __restrict__ W_in, const float* __restrict__ b_in,
    const float* __restrict__ W_out, const float* __restrict__ b_out,
    const float* __restrict__ c_p,
    const float* __restrict__ Lm_p,
    const float* __restrict__ iL_p,
    float* __restrict__ out)
{
    const int t    = threadIdx.x;
    const int lane = t & 63;
    const int wave = t >> 6;
    const int row  = blockIdx.x * 4 + wave;       // one wave per row
    const int h    = blockIdx.x / (S_DIM / 4);    // 192 blocks per h (exact)

    __shared__ __align__(16) float sh[W_DIM];     // sorted hinges (b128-aligned)
    __shared__ __align__(8)  float sAB[2 * NK];   // A,B pairs for this h
    __shared__ float th_s[W_DIM];                 // unsorted hinges
    __shared__ float sWin[W_DIM], sBin[W_DIM], sWout[W_DIM];
    __shared__ int   rk_s[W_DIM];                 // rank of hinge w
    __shared__ float pA[4 * NK], pB[4 * NK];      // partial A/B sums

    // ---- issue global loads first (HBM latency hides under table build) ----
    const float* rowp = attn + (size_t)row * S_DIM + lane * 12;
    float4 v0 = *(const float4*)(rowp);
    float4 v1 = *(const float4*)(rowp + 4);
    float4 v2 = *(const float4*)(rowp + 8);
    const float c   = c_p[0];
    const float thr = fabsf(Lm_p[0] * iL_p[0]);

    // ---- table build step 1: hinges + cache weights in LDS ----
    if (t < W_DIM) {
        float w1 = W_in[t], b = b_in[t];
        th_s[t] = (w1 != 0.0f) ? (-b / w1) : __builtin_inff();
        sWin[t] = w1;
        sBin[t] = b;
        sWout[t] = W_out[h * W_DIM + t];
    }
    __syncthreads();

    // ---- step 2: rank (ties by index) -> sorted hinge array ----
    if (t < W_DIM) {
        float mine = th_s[t];
        int r = 0;
        for (int v = 0; v < W_DIM; v++) {
            float o = th_s[v];
            if (o < mine || (o == mine && v < t)) r++;
        }
        rk_s[t] = r;
        sh[r]   = mine;
    }
    __syncthreads();

    // ---- step 3: A/B partial sums, 4 threads per interval k (t < 132) ----
    if (t < 4 * NK) {
        const int k = t >> 2, q = t & 3;
        float A = 0.0f, B = 0.0f;
#pragma unroll
        for (int j = 0; j < 8; j++) {
            const int w = q * 8 + j;
            float w1 = sWin[w], bv = sBin[w], ov = sWout[w];
            int   r  = rk_s[w];
            bool active = (w1 > 0.0f) ? (k > r)
                        : (w1 < 0.0f) ? (k <= r)
                        : (bv > 0.0f);
            if (active) { A += w1 * ov; B += bv * ov; }
        }
        pA[t] = A;
        pB[t] = B;
    }
    __syncthreads();

    // ---- step 4: combine partials (t < 33); overlapped with sigmoid below --
    if (t < NK) {
        float A = (pA[4*t] + pA[4*t+1]) + (pA[4*t+2] + pA[4*t+3]);
        float B = (pB[4*t] + pB[4*t+1]) + (pB[4*t+2] + pB[4*t+3]) + b_out[h];
        sAB[2*t]     = A;
        sAB[2*t + 1] = B;
    }

    // ---- table-independent element compute (all threads, hides step 4) ----
    float g[12] = { v0.x, v0.y, v0.z, v0.w, v1.x, v1.y, v1.z, v1.w,
                    v2.x, v2.y, v2.z, v2.w };
#pragma unroll
    for (int i = 0; i < 12; i++)
        g[i] = __builtin_amdgcn_rcpf(1.0f + __expf(-g[i]));

    // lane total, inclusive wave scan over lane totals
    float T0 = 0.0f;
#pragma unroll
    for (int i = 0; i < 12; i++) T0 += g[i];
    float P = T0;
#pragma unroll
    for (int d = 1; d < 64; d <<= 1) {
        float y = __shfl_up(P, d, 64);
        if (lane >= d) P += y;
    }
    const float total = __shfl(P, 63, 64);
    const float base  = total - P + T0;   // suffix sum at lane's first element

    const float den      = __logf(fabsf(c * fminf(total, thr)) + 1.0f) + EPS_F;
    // fold ln2 into inv_den so per-element log is raw v_log_f32 (log2)
    const float inv_den2 = 0.69314718056f * __builtin_amdgcn_rcpf(den);

    // phase 1: all 12 dist values (independent log chains)
    float dv[12];
    {
        float e = 0.0f;
#pragma unroll
        for (int i = 0; i < 12; i++) {
            float pos = base - e;            // suffix sum at element i
            e += g[i];
            dv[i] = __log2f(fabsf(c * pos) + 1.0f) * inv_den2;
        }
    }

    __syncthreads();   // tables complete

    // uniform hinge scalars for the register-select levels (LDS broadcasts)
    const float s3  = sh[3],  s7  = sh[7],  s11 = sh[11], s15 = sh[15];
    const float s19 = sh[19], s23 = sh[23], s27 = sh[27];

    // ---- phase 2: PWL search, two half-batches of 6 for explicit MLP ------
    float o[12];
#pragma unroll
    for (int half = 0; half < 2; half++) {
        const int i0 = half * 6;

        int    k4[6];
        float4 r[6];
#pragma unroll
        for (int j = 0; j < 6; j++) {
            const float d = dv[i0 + j];
            int k = 0;
            bool b1 = (s15 < d);             if (b1) k += 16;
            float l2 = b1 ? s23 : s7;
            bool b2 = (l2 < d);              if (b2) k += 8;
            float l3a = b2 ? s11 : s3;
            float l3b = b2 ? s27 : s19;
            float l3  = b1 ? l3b : l3a;
            if (l3 < d) k += 4;
            k4[j] = k;                       // k in {0,4,...,28}
        }
        // issue all 6 b128 reads (aligned; 8 distinct 16B slots tile banks)
#pragma unroll
        for (int j = 0; j < 6; j++)
            r[j] = *(const float4*)(&sh[k4[j]]);

        // resolve final k via register selects, then the 6 A/B reads
        float2 ab[6];
        float  dd[6];
#pragma unroll
        for (int j = 0; j < 6; j++) {
            const float d = dv[i0 + j];
            int k = k4[j];
            bool c2 = (r[j].y < d);          if (c2) k += 2;   // test s[k+1]
            float f1 = c2 ? r[j].z : r[j].x;                    // s[k] after +2
            bool c1 = (f1 < d);              if (c1) k += 1;
            float f0 = c1 ? (c2 ? r[j].w : r[j].y) : f1;        // s[k] after +1
            if (f0 < d) k += 1;              // final fixup -> k in [0,32]
            ab[j] = *(const float2*)(&sAB[2 * k]);
            dd[j] = d;
        }
#pragma unroll
        for (int j = 0; j < 6; j++)
            o[i0 + j] = fmaf(dd[j], ab[j].x, ab[j].y);   // A_k*d + B_k
    }

    float* op = out + (size_t)row * S_DIM + lane * 12;
    *(float4*)(op)     = make_float4(o[0], o[1], o[2],  o[3]);
    *(float4*)(op + 4) = make_float4(o[4], o[5], o[6],  o[7]);
    *(float4*)(op + 8) = make_float4(o[8], o[9], o[10], o[11]);
}

extern "C" void kernel_launch(void* const* d_in, const int* in_sizes, int n_in,
                              void* d_out, int out_size, void* d_ws, size_t ws_size,
                              hipStream_t stream) {
    const float* attn  = (const float*)d_in[0];
    const float* W_in  = (const float*)d_in[1];
    const float* b_in  = (const float*)d_in[2];
    const float* W_out = (const float*)d_in[3];
    const float* b_out = (const float*)d_in[4];
    const float* c_p   = (const float*)d_in[5];
    const float* Lm_p  = (const float*)d_in[6];
    const float* iL_p  = (const float*)d_in[7];
    float* out = (float*)d_out;
    (void)d_ws; (void)ws_size;

    const int rows = H_DIM * S_DIM;            // 9216 rows, one wave each
    cope_fused_kernel<<<rows / 4, 256, 0, stream>>>(
        attn, W_in, b_in, W_out, b_out, c_p, Lm_p, iL_p, out);
}